// Round 12
// baseline (122.228 us; speedup 1.0000x reference)
//
#include <hip/hip_runtime.h>
#include <hip/hip_fp16.h>
#include <math.h>

#define D_FEAT 128
#define EPS 1e-12f
#define CAP 128        // payload slots per row; Poisson(64) max deg ~110 < 128
#define CNT_STRIDE 16  // one counter per 64 B line

// ===========================================================================
// out = normalize(relu(sum_e ew_e * x_src)) — the 1/deg row scale cancels in
// the L2 normalize, so deg is never computed. Direct-append grouping (R10,
// proven): rank = atomicAdd(&cnt[t]); payload[t*CAP+rank] = src<<16|fp16(w).
// x pre-converted to fp16 (2.56 MB, fits per-XCD L2), fused into hist.
// R12 change: gather chunk body is a staged 32-wide pipeline —
//   32 bpermutes -> 32 back-to-back x-row loads -> FMA consume —
// lifting per-wave outstanding loads from ~4 to ~32 (R10 gather was ~88%
// stall at VALUBusy 12%, VGPR 16: latency-bound, not throughput-bound).
// Pipeline: memset(cnt 640KB) -> hist+convert -> gather(+relu+L2norm).
// ===========================================================================

__device__ inline float2 h2_to_f2(unsigned int u) {
    __half2 h = *reinterpret_cast<__half2*>(&u);
    return __half22float2(h);
}

// ---------------------------------------------------------------------------
// Stage 1 (fused): histogram append + x fp32->fp16 convert (R10, proven).
// ---------------------------------------------------------------------------
__global__ void hist_convert_kernel(const int* __restrict__ edge_i,
                                    const int* __restrict__ edge_j,
                                    const float* __restrict__ ew,
                                    const float* __restrict__ x,
                                    unsigned int* __restrict__ xh,
                                    int* __restrict__ cnt,
                                    unsigned int* __restrict__ payload,
                                    int E, int total4) {
    int i = blockIdx.x * blockDim.x + threadIdx.x;

    if (i < total4) {
        float4 v = ((const float4*)x)[i];
        __half2 h01 = __floats2half2_rn(v.x, v.y);
        __half2 h23 = __floats2half2_rn(v.z, v.w);
        uint2 o;
        o.x = *reinterpret_cast<unsigned int*>(&h01);
        o.y = *reinterpret_cast<unsigned int*>(&h23);
        ((uint2*)xh)[i] = o;
    }

    if (i < E) {
        int t = edge_i[i];
        int rank = atomicAdd(&cnt[(size_t)t * CNT_STRIDE], 1);
        if (rank < CAP) {
            unsigned short hw = __half_as_ushort(__float2half(ew[i]));
            payload[(size_t)t * CAP + rank] =
                ((unsigned int)edge_j[i] << 16) | (unsigned int)hw;
        }
    }
}

// ---------------------------------------------------------------------------
// Stage 2: gather + relu + L2 normalize. One wave per row; two 32-lane
// halves each cover all 128 feats (4 fp16/lane = uint2), halves consume
// edges j / j+32 of each 64-edge chunk. Chunk body: stage ALL 32 broadcasts,
// issue ALL 32 loads, then consume — 32 outstanding loads per wave.
// Padded lanes carry p=0 -> src=0 (hot line), w=0 -> contributes nothing.
// ---------------------------------------------------------------------------
__global__ void gather_norm_kernel(const int* __restrict__ cnt,
                                   const unsigned int* __restrict__ payload,
                                   const unsigned int* __restrict__ xh,
                                   float* __restrict__ out, int n) {
    int row  = (int)((blockIdx.x * (unsigned)blockDim.x + threadIdx.x) >> 6);
    int lane = threadIdx.x & 63;
    if (row >= n) return;

    int m = cnt[(size_t)row * CNT_STRIDE];
    if (m > CAP) m = CAP;

    const unsigned int* __restrict__ prow = payload + (size_t)row * CAP;
    const uint2* __restrict__ xr = (const uint2*)xh;  // 4 halves per uint2
    const int lane31  = lane & 31;
    const int halfsel = lane & 32;

    float4 a0 = {0.f,0.f,0.f,0.f}, a1 = {0.f,0.f,0.f,0.f};
    float4 a2 = {0.f,0.f,0.f,0.f}, a3 = {0.f,0.f,0.f,0.f};

    for (int base = 0; base < m; base += 64) {
        unsigned int p = 0;   // w = fp16(0) for padded lanes
        if (base + lane < m) p = prow[base + lane];

        // stage all 32 broadcasts (this half's edges)
        unsigned int pj[32];
        #pragma unroll
        for (int j = 0; j < 32; ++j)
            pj[j] = (unsigned int)__shfl((int)p, j + halfsel, 64);

        // issue all 32 row loads back-to-back (32 outstanding vmem ops)
        uint2 h[32];
        #pragma unroll
        for (int j = 0; j < 32; ++j)
            h[j] = xr[(size_t)(pj[j] >> 16) * 32 + lane31];

        // consume (round-robin over 4 accumulators for FMA ILP)
        #pragma unroll
        for (int j = 0; j < 32; ++j) {
            float w = __half2float(__ushort_as_half((unsigned short)(pj[j] & 0xffffu)));
            float2 f0 = h2_to_f2(h[j].x);
            float2 f1 = h2_to_f2(h[j].y);
            float4* a = (j & 3) == 0 ? &a0 : (j & 3) == 1 ? &a1 : (j & 3) == 2 ? &a2 : &a3;
            a->x = fmaf(f0.x, w, a->x);
            a->y = fmaf(f0.y, w, a->y);
            a->z = fmaf(f1.x, w, a->z);
            a->w = fmaf(f1.y, w, a->w);
        }
    }

    float4 acc;
    acc.x = (a0.x + a1.x) + (a2.x + a3.x);
    acc.y = (a0.y + a1.y) + (a2.y + a3.y);
    acc.z = (a0.z + a1.z) + (a2.z + a3.z);
    acc.w = (a0.w + a1.w) + (a2.w + a3.w);

    // combine the two halves (each covered all 128 feats for its edge subset)
    acc.x += __shfl_xor(acc.x, 32, 64);
    acc.y += __shfl_xor(acc.y, 32, 64);
    acc.z += __shfl_xor(acc.z, 32, 64);
    acc.w += __shfl_xor(acc.w, 32, 64);

    acc.x = fmaxf(acc.x, 0.0f);
    acc.y = fmaxf(acc.y, 0.0f);
    acc.z = fmaxf(acc.z, 0.0f);
    acc.w = fmaxf(acc.w, 0.0f);

    float ss = acc.x * acc.x + acc.y * acc.y + acc.z * acc.z + acc.w * acc.w;
    #pragma unroll
    for (int off = 16; off > 0; off >>= 1) ss += __shfl_xor(ss, off, 64);

    float scale = 1.0f / fmaxf(sqrtf(ss), EPS);
    acc.x *= scale;
    acc.y *= scale;
    acc.z *= scale;
    acc.w *= scale;

    if (lane < 32) {
        ((float4*)out)[(size_t)row * 32 + lane31] = acc;
    }
}

// ===========================================================================
// Last-resort fallback (proven R1): atomic scatter, needs n*4 B of ws.
// ===========================================================================
__global__ void deg_kernel(const int* __restrict__ edge_i,
                           const float* __restrict__ ew,
                           float* __restrict__ deg, int E) {
    int e = blockIdx.x * blockDim.x + threadIdx.x;
    if (e < E) atomicAdd(&deg[edge_i[e]], ew[e]);
}

__global__ void scatter_kernel(const int* __restrict__ edge_j,
                               const int* __restrict__ edge_i,
                               const float* __restrict__ ew,
                               const float* __restrict__ deg,
                               const float* __restrict__ x,
                               float* __restrict__ out, int E) {
    int wave = (int)((blockIdx.x * (unsigned)blockDim.x + threadIdx.x) >> 6);
    int lane = threadIdx.x & 63;
    if (wave >= E) return;
    int tgt = edge_i[wave];
    int src = edge_j[wave];
    float w = ew[wave] / deg[tgt];
    const float2* xr = (const float2*)(x + (size_t)src * D_FEAT);
    float2 v = xr[lane];
    float* o = out + (size_t)tgt * D_FEAT + lane * 2;
    atomicAdd(o,     v.x * w);
    atomicAdd(o + 1, v.y * w);
}

__global__ void norm_kernel(float* __restrict__ out, int n) {
    int row = (int)((blockIdx.x * (unsigned)blockDim.x + threadIdx.x) >> 6);
    int lane = threadIdx.x & 63;
    if (row >= n) return;
    float2* o = (float2*)(out + (size_t)row * D_FEAT);
    float2 v = o[lane];
    v.x = fmaxf(v.x, 0.0f);
    v.y = fmaxf(v.y, 0.0f);
    float ss = v.x * v.x + v.y * v.y;
    #pragma unroll
    for (int off = 32; off > 0; off >>= 1) ss += __shfl_xor(ss, off, 64);
    float scale = 1.0f / fmaxf(sqrtf(ss), EPS);
    v.x *= scale;
    v.y *= scale;
    o[lane] = v;
}

// ===========================================================================
// Launch. ws layout (64 B aligned):
//   xh (n*128*2 B = 2.56 MB) | cnt (n*CNT_STRIDE*4 B = 640 KB)
//   | payload (n*CAP*4 B = 5.12 MB)    total ~8.3 MB (ws is 256 MiB).
// ===========================================================================
static inline size_t align64(size_t v) { return (v + 63) & ~(size_t)63; }

extern "C" void kernel_launch(void* const* d_in, const int* in_sizes, int n_in,
                              void* d_out, int out_size, void* d_ws, size_t ws_size,
                              hipStream_t stream) {
    const float* x    = (const float*)d_in[0];
    const int*   edge = (const int*)d_in[1];
    const float* ew   = (const float*)d_in[2];
    float*       out  = (float*)d_out;

    const int E = in_sizes[2];            // 640000
    const int n = in_sizes[0] / D_FEAT;   // 10000

    const int* edge_j = edge;                    // sources (row 0)
    const int* edge_i = edge + 2 * (size_t)E;    // targets (row 2)

    const size_t off_cnt = align64((size_t)n * D_FEAT * 2);
    const size_t cnt_sz  = (size_t)n * CNT_STRIDE * 4;
    const size_t off_pl  = align64(off_cnt + cnt_sz);
    const size_t need    = off_pl + (size_t)n * CAP * 4;

    if (ws_size >= need) {
        char* ws = (char*)d_ws;
        unsigned int* xh      = (unsigned int*)ws;
        int*          cnt     = (int*)(ws + off_cnt);
        unsigned int* payload = (unsigned int*)(ws + off_pl);

        const int total4 = n * D_FEAT / 4;   // 320000 float4 groups

        hipMemsetAsync(cnt, 0, cnt_sz, stream);
        hist_convert_kernel<<<(E + 255) / 256, 256, 0, stream>>>(edge_i, edge_j, ew,
                                                                 x, xh, cnt, payload,
                                                                 E, total4);
        gather_norm_kernel<<<(n + 3) / 4, 256, 0, stream>>>(cnt, payload, xh, out, n);
    } else {
        float* deg = (float*)d_ws;
        hipMemsetAsync(deg, 0, (size_t)n * sizeof(float), stream);
        hipMemsetAsync(out, 0, (size_t)out_size * sizeof(float), stream);
        deg_kernel<<<(E + 255) / 256, 256, 0, stream>>>(edge_i, ew, deg, E);
        scatter_kernel<<<(E + 3) / 4, 256, 0, stream>>>(edge_j, edge_i, ew, deg, x, out, E);
        norm_kernel<<<(n + 3) / 4, 256, 0, stream>>>(out, n);
    }
}

// Round 13
// 108.343 us; speedup vs baseline: 1.1282x; 1.1282x over previous
//
#include <hip/hip_runtime.h>
#include <hip/hip_fp16.h>
#include <math.h>

#define D_FEAT 128
#define EPS 1e-12f
#define CAP 128       // dense payload slots per row; max degree ~110 (Poisson 64)
#define NBLK 64       // deterministic edge chunks; chunk b = edges [b*EPB,(b+1)*EPB)
#define NPAD 10240    // padded node count (multiple of 1024)

// ===========================================================================
// out = normalize(relu(sum_e ew_e * x_src)) — the 1/deg row scale cancels in
// the L2 normalize, so deg is never computed.
// R13: ZERO global atomics. R8-R12 showed atomic-with-return throughput
// (~15 Gop/s device-wide) made the 640K-return histogram a 44 us floor that
// neither counter padding (R10) nor 8x address spreading (R11) moved.
// Deterministic counting sort instead:
//   A: per-chunk LDS histogram -> u8 cntg[b][t]   (+ fused x->fp16 convert)
//   B: per-target prefix over chunks -> u8 baseg[b][t], degg[t]
//   C: re-read chunk, LDS-atomic local rank, plain store
//      payload[t*CAP + baseg[b][t] + lrank] = src<<16 | fp16(w)
//   G: R10-proven gather + relu + L2norm (dense 64-entry rows)
// No memsets: every kernel initializes what it reads.
// ===========================================================================

__device__ inline float2 h2_to_f2(unsigned int u) {
    __half2 h = *reinterpret_cast<__half2*>(&u);
    return __half22float2(h);
}

// ---------------------------------------------------------------------------
// Phase A: per-chunk histogram (LDS) + fused x fp32->fp16 convert.
// 64 blocks x 1024 threads; block b owns edges [b*EPB, b*EPB+EPB).
// ---------------------------------------------------------------------------
__global__ __launch_bounds__(1024)
void count_convert_kernel(const int* __restrict__ edge_i,
                          const float* __restrict__ x,
                          unsigned int* __restrict__ xh,
                          unsigned char* __restrict__ cntg,  // [NBLK][NPAD]
                          int E, int total4) {
    __shared__ unsigned int lc[NPAD];   // 40 KB
    const int b   = blockIdx.x;
    const int tid = threadIdx.x;
    const int EPB = E / NBLK;

    for (int i = tid; i < NPAD; i += 1024) lc[i] = 0;
    __syncthreads();

    // fused convert (grid-stride over all float4 groups)
    for (int i = b * 1024 + tid; i < total4; i += NBLK * 1024) {
        float4 v = ((const float4*)x)[i];
        __half2 h01 = __floats2half2_rn(v.x, v.y);
        __half2 h23 = __floats2half2_rn(v.z, v.w);
        uint2 o;
        o.x = *reinterpret_cast<unsigned int*>(&h01);
        o.y = *reinterpret_cast<unsigned int*>(&h23);
        ((uint2*)xh)[i] = o;
    }

    // count this chunk's targets
    const int e0 = b * EPB;
    for (int k = tid; k < EPB; k += 1024)
        atomicAdd(&lc[edge_i[e0 + k]], 1u);
    __syncthreads();

    for (int i = tid; i < NPAD; i += 1024) {
        unsigned int c = lc[i];
        cntg[(size_t)b * NPAD + i] = (unsigned char)(c > 255u ? 255u : c);
    }
}

// ---------------------------------------------------------------------------
// Phase B: per-target exclusive prefix over the 64 chunks.
// grid: NPAD threads total (40 blocks x 256). t = global thread id.
// ---------------------------------------------------------------------------
__global__ void base_kernel(const unsigned char* __restrict__ cntg,
                            unsigned char* __restrict__ baseg,  // [NBLK][NPAD]
                            int* __restrict__ degg) {
    int t = blockIdx.x * blockDim.x + threadIdx.x;
    if (t >= NPAD) return;
    unsigned int pre = 0;
    #pragma unroll
    for (int b = 0; b < NBLK; ++b) {
        unsigned int c = cntg[(size_t)b * NPAD + t];
        baseg[(size_t)b * NPAD + t] = (unsigned char)(pre > 255u ? 255u : pre);
        pre += c;
    }
    degg[t] = (int)pre;
}

// ---------------------------------------------------------------------------
// Phase C: placement. Block b re-reads its chunk; local rank from LDS
// atomics; slot = t*CAP + baseg[b][t] + lrank. Plain stores (no returns).
// ---------------------------------------------------------------------------
__global__ __launch_bounds__(1024)
void place_kernel(const int* __restrict__ edge_i,
                  const int* __restrict__ edge_j,
                  const float* __restrict__ ew,
                  const unsigned char* __restrict__ baseg,
                  unsigned int* __restrict__ payload, int E) {
    __shared__ unsigned int  lcnt[NPAD];    // 40 KB
    __shared__ unsigned char lbase[NPAD];   // 10 KB
    const int b   = blockIdx.x;
    const int tid = threadIdx.x;
    const int EPB = E / NBLK;

    for (int i = tid; i < NPAD; i += 1024) {
        lcnt[i]  = 0;
        lbase[i] = baseg[(size_t)b * NPAD + i];
    }
    __syncthreads();

    const int e0 = b * EPB;
    for (int k = tid; k < EPB; k += 1024) {
        int e = e0 + k;
        int t = edge_i[e];
        int lr = (int)atomicAdd(&lcnt[t], 1u);
        int slot = t * CAP + (int)lbase[t] + lr;
        if (slot < t * CAP + CAP) {   // safety clamp (never expected)
            unsigned short hw = __half_as_ushort(__float2half(ew[e]));
            payload[slot] = ((unsigned int)edge_j[e] << 16) | (unsigned int)hw;
        }
    }
}

// ---------------------------------------------------------------------------
// Phase G: gather + relu + L2 normalize (R10-proven body). One wave per row;
// two 32-lane halves each cover all 128 feats (uint2 = 4 fp16), consuming
// edges j / j+32 of each 64-edge chunk; 4-way unroll for load MLP.
// ---------------------------------------------------------------------------
__global__ void gather_norm_kernel(const int* __restrict__ degg,
                                   const unsigned int* __restrict__ payload,
                                   const unsigned int* __restrict__ xh,
                                   float* __restrict__ out, int n) {
    int row  = (int)((blockIdx.x * (unsigned)blockDim.x + threadIdx.x) >> 6);
    int lane = threadIdx.x & 63;
    if (row >= n) return;

    int m = degg[row];
    if (m > CAP) m = CAP;

    const unsigned int* __restrict__ prow = payload + (size_t)row * CAP;
    const uint2* __restrict__ xr = (const uint2*)xh;
    const int lane31  = lane & 31;
    const int halfsel = lane & 32;

    float4 a0 = {0.f,0.f,0.f,0.f}, a1 = {0.f,0.f,0.f,0.f};
    float4 a2 = {0.f,0.f,0.f,0.f}, a3 = {0.f,0.f,0.f,0.f};

    for (int base = 0; base < m; base += 64) {
        int mm = m - base;
        if (mm > 64) mm = 64;
        unsigned int p = 0;   // w = fp16(0) for padded lanes -> contributes 0
        if (lane < mm) p = prow[base + lane];

        int jmax = mm < 32 ? mm : 32;
        int j = 0;
        for (; j + 3 < jmax; j += 4) {
            unsigned int p0 = (unsigned int)__shfl((int)p, j     + halfsel, 64);
            unsigned int p1 = (unsigned int)__shfl((int)p, j + 1 + halfsel, 64);
            unsigned int p2 = (unsigned int)__shfl((int)p, j + 2 + halfsel, 64);
            unsigned int p3 = (unsigned int)__shfl((int)p, j + 3 + halfsel, 64);
            uint2 h0 = xr[(size_t)(p0 >> 16) * 32 + lane31];
            uint2 h1 = xr[(size_t)(p1 >> 16) * 32 + lane31];
            uint2 h2 = xr[(size_t)(p2 >> 16) * 32 + lane31];
            uint2 h3 = xr[(size_t)(p3 >> 16) * 32 + lane31];
            float w0 = __half2float(__ushort_as_half((unsigned short)(p0 & 0xffffu)));
            float w1 = __half2float(__ushort_as_half((unsigned short)(p1 & 0xffffu)));
            float w2 = __half2float(__ushort_as_half((unsigned short)(p2 & 0xffffu)));
            float w3 = __half2float(__ushort_as_half((unsigned short)(p3 & 0xffffu)));
            float2 f;
            f = h2_to_f2(h0.x); a0.x = fmaf(f.x, w0, a0.x); a0.y = fmaf(f.y, w0, a0.y);
            f = h2_to_f2(h0.y); a0.z = fmaf(f.x, w0, a0.z); a0.w = fmaf(f.y, w0, a0.w);
            f = h2_to_f2(h1.x); a1.x = fmaf(f.x, w1, a1.x); a1.y = fmaf(f.y, w1, a1.y);
            f = h2_to_f2(h1.y); a1.z = fmaf(f.x, w1, a1.z); a1.w = fmaf(f.y, w1, a1.w);
            f = h2_to_f2(h2.x); a2.x = fmaf(f.x, w2, a2.x); a2.y = fmaf(f.y, w2, a2.y);
            f = h2_to_f2(h2.y); a2.z = fmaf(f.x, w2, a2.z); a2.w = fmaf(f.y, w2, a2.w);
            f = h2_to_f2(h3.x); a3.x = fmaf(f.x, w3, a3.x); a3.y = fmaf(f.y, w3, a3.y);
            f = h2_to_f2(h3.y); a3.z = fmaf(f.x, w3, a3.z); a3.w = fmaf(f.y, w3, a3.w);
        }
        for (; j < jmax; ++j) {
            unsigned int p0 = (unsigned int)__shfl((int)p, j + halfsel, 64);
            float w0 = __half2float(__ushort_as_half((unsigned short)(p0 & 0xffffu)));
            uint2 h0 = xr[(size_t)(p0 >> 16) * 32 + lane31];
            float2 f;
            f = h2_to_f2(h0.x); a0.x = fmaf(f.x, w0, a0.x); a0.y = fmaf(f.y, w0, a0.y);
            f = h2_to_f2(h0.y); a0.z = fmaf(f.x, w0, a0.z); a0.w = fmaf(f.y, w0, a0.w);
        }
    }

    float4 acc;
    acc.x = (a0.x + a1.x) + (a2.x + a3.x);
    acc.y = (a0.y + a1.y) + (a2.y + a3.y);
    acc.z = (a0.z + a1.z) + (a2.z + a3.z);
    acc.w = (a0.w + a1.w) + (a2.w + a3.w);

    acc.x += __shfl_xor(acc.x, 32, 64);
    acc.y += __shfl_xor(acc.y, 32, 64);
    acc.z += __shfl_xor(acc.z, 32, 64);
    acc.w += __shfl_xor(acc.w, 32, 64);

    acc.x = fmaxf(acc.x, 0.0f);
    acc.y = fmaxf(acc.y, 0.0f);
    acc.z = fmaxf(acc.z, 0.0f);
    acc.w = fmaxf(acc.w, 0.0f);

    float ss = acc.x * acc.x + acc.y * acc.y + acc.z * acc.z + acc.w * acc.w;
    #pragma unroll
    for (int off = 16; off > 0; off >>= 1) ss += __shfl_xor(ss, off, 64);

    float scale = 1.0f / fmaxf(sqrtf(ss), EPS);
    acc.x *= scale;
    acc.y *= scale;
    acc.z *= scale;
    acc.w *= scale;

    if (lane < 32) {
        ((float4*)out)[(size_t)row * 32 + lane31] = acc;
    }
}

// ===========================================================================
// Last-resort fallback (proven R1): atomic scatter, needs n*4 B of ws.
// ===========================================================================
__global__ void deg_kernel(const int* __restrict__ edge_i,
                           const float* __restrict__ ew,
                           float* __restrict__ deg, int E) {
    int e = blockIdx.x * blockDim.x + threadIdx.x;
    if (e < E) atomicAdd(&deg[edge_i[e]], ew[e]);
}

__global__ void scatter_kernel(const int* __restrict__ edge_j,
                               const int* __restrict__ edge_i,
                               const float* __restrict__ ew,
                               const float* __restrict__ deg,
                               const float* __restrict__ x,
                               float* __restrict__ out, int E) {
    int wave = (int)((blockIdx.x * (unsigned)blockDim.x + threadIdx.x) >> 6);
    int lane = threadIdx.x & 63;
    if (wave >= E) return;
    int tgt = edge_i[wave];
    int src = edge_j[wave];
    float w = ew[wave] / deg[tgt];
    const float2* xr = (const float2*)(x + (size_t)src * D_FEAT);
    float2 v = xr[lane];
    float* o = out + (size_t)tgt * D_FEAT + lane * 2;
    atomicAdd(o,     v.x * w);
    atomicAdd(o + 1, v.y * w);
}

__global__ void norm_kernel(float* __restrict__ out, int n) {
    int row = (int)((blockIdx.x * (unsigned)blockDim.x + threadIdx.x) >> 6);
    int lane = threadIdx.x & 63;
    if (row >= n) return;
    float2* o = (float2*)(out + (size_t)row * D_FEAT);
    float2 v = o[lane];
    v.x = fmaxf(v.x, 0.0f);
    v.y = fmaxf(v.y, 0.0f);
    float ss = v.x * v.x + v.y * v.y;
    #pragma unroll
    for (int off = 32; off > 0; off >>= 1) ss += __shfl_xor(ss, off, 64);
    float scale = 1.0f / fmaxf(sqrtf(ss), EPS);
    v.x *= scale;
    v.y *= scale;
    o[lane] = v;
}

// ===========================================================================
// Launch. ws layout (64 B aligned):
//   xh (n*128*2 = 2.56 MB) | cntg (NBLK*NPAD = 640 KB) | baseg (640 KB)
//   | degg (NPAD*4 = 40 KB) | payload (n*CAP*4 = 5.12 MB)  total ~9 MB.
// Requires E % NBLK == 0 (640000/64 = 10000 exactly); else fallback.
// ===========================================================================
static inline size_t align64(size_t v) { return (v + 63) & ~(size_t)63; }

extern "C" void kernel_launch(void* const* d_in, const int* in_sizes, int n_in,
                              void* d_out, int out_size, void* d_ws, size_t ws_size,
                              hipStream_t stream) {
    const float* x    = (const float*)d_in[0];
    const int*   edge = (const int*)d_in[1];
    const float* ew   = (const float*)d_in[2];
    float*       out  = (float*)d_out;

    const int E = in_sizes[2];            // 640000
    const int n = in_sizes[0] / D_FEAT;   // 10000

    const int* edge_j = edge;                    // sources (row 0)
    const int* edge_i = edge + 2 * (size_t)E;    // targets (row 2)

    const size_t off_cntg  = align64((size_t)n * D_FEAT * 2);
    const size_t off_baseg = align64(off_cntg + (size_t)NBLK * NPAD);
    const size_t off_degg  = align64(off_baseg + (size_t)NBLK * NPAD);
    const size_t off_pl    = align64(off_degg + (size_t)NPAD * 4);
    const size_t need      = off_pl + (size_t)n * CAP * 4;

    if (ws_size >= need && (E % NBLK) == 0 && n <= NPAD) {
        char* ws = (char*)d_ws;
        unsigned int*  xh      = (unsigned int*)ws;
        unsigned char* cntg    = (unsigned char*)(ws + off_cntg);
        unsigned char* baseg   = (unsigned char*)(ws + off_baseg);
        int*           degg    = (int*)(ws + off_degg);
        unsigned int*  payload = (unsigned int*)(ws + off_pl);

        const int total4 = n * D_FEAT / 4;   // 320000 float4 groups

        count_convert_kernel<<<NBLK, 1024, 0, stream>>>(edge_i, x, xh, cntg,
                                                        E, total4);
        base_kernel<<<NPAD / 256, 256, 0, stream>>>(cntg, baseg, degg);
        place_kernel<<<NBLK, 1024, 0, stream>>>(edge_i, edge_j, ew, baseg,
                                                payload, E);
        gather_norm_kernel<<<(n + 3) / 4, 256, 0, stream>>>(degg, payload, xh,
                                                            out, n);
    } else {
        float* deg = (float*)d_ws;
        hipMemsetAsync(deg, 0, (size_t)n * sizeof(float), stream);
        hipMemsetAsync(out, 0, (size_t)out_size * sizeof(float), stream);
        deg_kernel<<<(E + 255) / 256, 256, 0, stream>>>(edge_i, ew, deg, E);
        scatter_kernel<<<(E + 3) / 4, 256, 0, stream>>>(edge_j, edge_i, ew, deg, x, out, E);
        norm_kernel<<<(n + 3) / 4, 256, 0, stream>>>(out, n);
    }
}